// Round 9
// baseline (239.251 us; speedup 1.0000x reference)
//
#include <hip/hip_runtime.h>
#include <math.h>

#define NFEAT  128
#define HC     256     // HEADS*NHID
#define HEADS  8
#define NHID   32
#define NCLASS 40

#define INV_LN2 1.44269504088896340736f

typedef unsigned int  uint;
typedef unsigned short ushort;
typedef unsigned char uchar;

typedef __attribute__((ext_vector_type(8))) short bf16x8;
typedef __attribute__((ext_vector_type(4))) float f32x4;
typedef __attribute__((ext_vector_type(2))) float f32x2;

union U8 { uint4 u; bf16x8 v; };

// bf16 helpers (RNE pack, cheap unpack)
__device__ __forceinline__ uint f2bf1(float f) {
    uint b = __float_as_uint(f);
    b += 0x7FFFu + ((b >> 16) & 1u);
    return b >> 16;
}
__device__ __forceinline__ uint packbf(float lo, float hi) {
    return f2bf1(lo) | (f2bf1(hi) << 16);
}

// fp8 e4m3 (OCP) via HW converts
__device__ __forceinline__ uchar f2fp8(float v) {
    return (uchar)(__builtin_amdgcn_cvt_pk_fp8_f32(v, v, 0, false) & 0xFF);
}
__device__ __forceinline__ float fp8tof(uint byte) {
    auto v2 = __builtin_amdgcn_cvt_pk_f32_fp8((int)byte, false);
    return v2[0];
}

// cross-lane pull with precomputed byte address (addr = src_lane*4)
__device__ __forceinline__ float bperm(int addr, float v) {
    return __int_as_float(__builtin_amdgcn_ds_bpermute(addr, __float_as_int(v)));
}
__device__ __forceinline__ int bperm_i(int addr, int v) {
    return __builtin_amdgcn_ds_bpermute(addr, v);
}

// ---------------- hist (rank only, coalesced store) + weight prep ----------------
// Round-7 proven form: atomic return feeds a COALESCED rank store; the random
// scatter is a separate streaming phase fused with gemm1. (Round-8's fused
// atomic->random-store XCD variant was latency-serialized: 48us @ 3.7% VALU.)

#define HU 8
#define PREPB 23
__global__ __launch_bounds__(256)
void k_hist_prep(const int* __restrict__ dst, int E, int* deg,
                 int* __restrict__ rank,
                 const float* __restrict__ W1,
                 const float* __restrict__ attS, const float* __restrict__ attD,
                 const float* __restrict__ W2,
                 const float* __restrict__ a2sw, const float* __restrict__ a2dw,
                 ushort* __restrict__ Wb1, ushort* __restrict__ Wb2) {
    int blk = blockIdx.x;
    int t = threadIdx.x;
    if (blk >= PREPB) {
        int tid = (blk - PREPB) * 256 + t;
        int stride = (gridDim.x - PREPB) * 256;
#pragma unroll
        for (int j = 0; j < HU; ++j) {
            int i = tid + j * stride;
            if (i < E) rank[i] = atomicAdd(&deg[dst[i]], 1);
        }
        return;
    }
    // ---- prep ----
    float f[8];
    if (blk < 17) {
        int g = blk * 256 + t;
        int lane = g & 63;
        int step = (g >> 6) & 3;
        int tile = g >> 8;
        int k0 = step * 32 + (lane >> 4) * 8;
        if (tile < 16) {
            int ncol = tile * 16 + (lane & 15);
#pragma unroll
            for (int j = 0; j < 8; ++j) f[j] = W1[(size_t)(k0 + j) * HC + ncol];
        } else {
            int cc = lane & 15;
            int h = cc & 7;
            const float* av = (cc < 8) ? attS : attD;
#pragma unroll
            for (int j = 0; j < 8; ++j) {
                const float* wr = W1 + (size_t)(k0 + j) * HC + h * 32;
                float s = 0.f;
#pragma unroll
                for (int c = 0; c < 32; ++c) s += wr[c] * av[h * 32 + c];
                f[j] = s * INV_LN2;   // exp2-domain attention logits
            }
        }
        uint4 o;
        o.x = packbf(f[0], f[1]);
        o.y = packbf(f[2], f[3]);
        o.z = packbf(f[4], f[5]);
        o.w = packbf(f[6], f[7]);
        *(uint4*)(Wb1 + (size_t)g * 8) = o;
    } else {
        int g = (blk - 17) * 256 + t;      // 0..1535
        if (g >= 3 * 8 * 64) return;
        int lane = g & 63;
        int ks = (g >> 6) & 7;
        int nt = g >> 9;
        int cc = lane & 15;
        int ncol = nt * 16 + cc;
        int k0 = ks * 32 + (lane >> 4) * 8;
        if (ncol < NCLASS) {
#pragma unroll
            for (int j = 0; j < 8; ++j) f[j] = W2[(size_t)(k0 + j) * NCLASS + ncol];
        } else if (ncol <= 41) {
            const float* av = (ncol == 40) ? a2sw : a2dw;
#pragma unroll
            for (int j = 0; j < 8; ++j) {
                const float* wr = W2 + (size_t)(k0 + j) * NCLASS;
                float s = 0.f;
#pragma unroll
                for (int c = 0; c < NCLASS; ++c) s += wr[c] * av[c];
                f[j] = s * INV_LN2;   // exp2-domain attention logits
            }
        } else {
#pragma unroll
            for (int j = 0; j < 8; ++j) f[j] = 0.f;
        }
        uint4 o;
        o.x = packbf(f[0], f[1]);
        o.y = packbf(f[2], f[3]);
        o.z = packbf(f[4], f[5]);
        o.w = packbf(f[6], f[7]);
        *(uint4*)(Wb2 + (size_t)g * 8) = o;
    }
}

// ---------------- fused scatter + GEMM1 ----------------
#define SU 4
__global__ __launch_bounds__(256)
void k_scatter_gemm1(const int* __restrict__ srcE, const int* __restrict__ dstE,
                     const int* __restrict__ rank, int E,
                     int* __restrict__ srcs, int scb,
                     const float* __restrict__ x, const ushort* __restrict__ Wb,
                     int n, uchar* __restrict__ h1f8, float* __restrict__ a1x) {
    __shared__ uint Xs[64 * 68];        // 17.4 KB; aliased as Cs[64][272]B later
    int t = threadIdx.x;
    if (blockIdx.x < scb) {
        // ---- scatter: 4-edge packets, vectorized streaming loads ----
        int tid = blockIdx.x * 256 + t;
        int stride = scb * 256;
        int P = (E + 3) >> 2;
#pragma unroll
        for (int g = 0; g < SU; ++g) {
            int pk = tid + g * stride;
            if (pk >= P) continue;
            int i0 = pk * 4;
            if (i0 + 4 <= E) {
                int4 d4 = *(const int4*)(dstE + i0);
                int4 r4 = *(const int4*)(rank + i0);
                int4 s4 = *(const int4*)(srcE + i0);
                if (r4.x < 64) srcs[((size_t)d4.x << 6) + r4.x] = s4.x;
                if (r4.y < 64) srcs[((size_t)d4.y << 6) + r4.y] = s4.y;
                if (r4.z < 64) srcs[((size_t)d4.z << 6) + r4.z] = s4.z;
                if (r4.w < 64) srcs[((size_t)d4.w << 6) + r4.w] = s4.w;
            } else {
                for (int i = i0; i < E; ++i) {
                    int r = rank[i];
                    if (r < 64) srcs[((size_t)dstE[i] << 6) + r] = srcE[i];
                }
            }
        }
        return;
    }
    // ---- gemm1 ----
    int lane = t & 63;
    int w = t >> 6;
    int n0 = (blockIdx.x - scb) * 64;

#pragma unroll
    for (int j = 0; j < 8; ++j) {
        int f4 = t + j * 256;
        int node = f4 >> 5;
        int k4 = (f4 & 31) * 4;
        int gn = n0 + node;
        float4 v = make_float4(0.f, 0.f, 0.f, 0.f);
        if (gn < n) v = *(const float4*)(x + (size_t)gn * NFEAT + k4);
        uint2 pk;
        pk.x = packbf(v.x, v.y);
        pk.y = packbf(v.z, v.w);
        *(uint2*)(Xs + node * 68 + (k4 >> 1)) = pk;
    }
    __syncthreads();

    int m = lane & 15;
    int q4 = (lane >> 4) * 4;
    bf16x8 Af[4];
#pragma unroll
    for (int ks = 0; ks < 4; ++ks) {
        U8 a;
        a.u = *(const uint4*)(Xs + (w * 16 + m) * 68 + ks * 16 + q4);
        Af[ks] = a.v;
    }
    __syncthreads();

    f32x4 acc[17];
#pragma unroll
    for (int i = 0; i < 17; ++i) acc[i] = (f32x4){0.f, 0.f, 0.f, 0.f};

    const bf16x8* Bf = (const bf16x8*)Wb;
#pragma unroll
    for (int ks = 0; ks < 4; ++ks) {
#pragma unroll
        for (int nt = 0; nt < 17; ++nt) {
            bf16x8 bv = Bf[(size_t)(nt * 4 + ks) * 64 + lane];
            acc[nt] = __builtin_amdgcn_mfma_f32_16x16x32_bf16(Af[ks], bv, acc[nt], 0, 0, 0);
        }
    }

    int cc = lane & 15;
    int r0 = (lane >> 4) * 4;

    // attention tile (nt=16): col cc -> a1x[gn*16+cc] (0..7 src heads, 8..15 dst)
#pragma unroll
    for (int r = 0; r < 4; ++r) {
        int gn = n0 + w * 16 + r0 + r;
        if (gn < n) a1x[(size_t)gn * 16 + cc] = acc[16][r];
    }

    uchar* CsB = (uchar*)Xs;
#pragma unroll
    for (int nt = 0; nt < 16; ++nt) {
#pragma unroll
        for (int r = 0; r < 4; ++r)
            CsB[(w * 16 + r0 + r) * 272 + nt * 16 + cc] = f2fp8(acc[nt][r]);
    }
    __syncthreads();

    int node_local = t >> 2;
    int q = t & 3;
    int gn = n0 + node_local;
    if (gn < n) {
        const uchar* crow = CsB + node_local * 272 + q * 64;
        uchar* hp = h1f8 + (size_t)gn * HC + q * 64;
#pragma unroll
        for (int i = 0; i < 4; ++i)
            *(uint4*)(hp + i * 16) = *(const uint4*)(crow + i * 16);
    }
}

// ---------------- FUSED Layer-1 aggregation + GEMM2 ----------------
// 1024-thread block = 16 waves = 64 dst nodes (wave w: nodes w*4..w*4+3,
// serial). Agg results (bf16) land DIRECTLY in the gemm2 LDS tile -> the
// hgb global round-trip (25 MB write + 26 MB read) and one dispatch vanish.
// Phase 2 = gemm2 MFMA (waves 0-3) + fp8/embedded-a2 epilogue, in-place.
// Agg inner loop = round-6 proven form (2-deep A/B, no per-j branches).
__global__ __launch_bounds__(1024)
void k_agg1_gemm2(const uint* __restrict__ h1u, const float* __restrict__ a1x,
                  const float* __restrict__ b1, const int* __restrict__ deg,
                  const int* __restrict__ srcs, const ushort* __restrict__ Wb2,
                  int n, uchar* __restrict__ h2f8) {
    __shared__ uint Xs[64 * 132];       // 33.8 KB; agg out tile + gemm2 CsB alias
    int t = threadIdx.x;
    int lane = t & 63;
    int w = t >> 6;                     // 0..15
    int n0 = blockIdx.x * 64;

    // ---- phase 1: aggregate 4 nodes per wave into Xs ----
    int vj = lane >> 3;
    int hh = lane & 7;
    int hacc = lane >> 3;
    const char* a1xb = (const char*)a1x;
    int ax8  = (lane ^ 8)  << 2;
    int ax16 = (lane ^ 16) << 2;
    int ax32 = (lane ^ 32) << 2;
    int bpc  = hacc << 2;
    int bpp[8];
#pragma unroll
    for (int j = 0; j < 8; ++j) bpp[j] = ((j << 3) + hacc) << 2;
    float4 bv = *(const float4*)(b1 + lane * 4);

    for (int k = 0; k < 4; ++k) {
        int node_local = w * 4 + k;
        int wid = n0 + node_local;
        if (wid < n) {
            wid = __builtin_amdgcn_readfirstlane(wid);
            float adn = a1x[(size_t)wid * 16 + 8 + hh];
            int degw = __builtin_amdgcn_readfirstlane(deg[wid]);
            degw = (degw < 63) ? degw : 63;
            int cnt = degw + 1;                  // + virtual self-loop
            int sv_full = srcs[((size_t)wid << 6) + lane];
            int sv_pad = (lane < degw) ? sv_full : wid;

            float s = 0.f;
            f32x2 acc01 = (f32x2){0.f, 0.f};
            f32x2 acc23 = (f32x2){0.f, 0.f};

            struct Chunk { float av; uint hv[8]; };
            Chunk A, B;

#define LOADC1(C, base) do {                                                   \
    int idxl_ = (base) + vj;                                                   \
    int svv_ = bperm_i(idxl_ << 2, sv_pad);                                    \
    (C).av = *(const float*)(a1xb + ((size_t)(uint)svv_ << 6) + ((uint)hh << 2)); \
    _Pragma("unroll")                                                          \
    for (int j_ = 0; j_ < 8; ++j_) {                                           \
        int sn_ = __builtin_amdgcn_readlane(sv_pad, (base) + j_);              \
        (C).hv[j_] = h1u[(size_t)(uint)sn_ * 64 + lane];                       \
    }                                                                          \
} while (0)

#define CONSC1(C, base) do {                                                   \
    int idxl_ = (base) + vj;                                                   \
    float a_ = (C).av + adn;                                                   \
    float e_ = fmaxf(a_, 0.2f * a_);                                           \
    float p_ = (idxl_ < cnt) ? __builtin_exp2f(e_) : 0.f;                      \
    s += p_;                                                                   \
    _Pragma("unroll")                                                          \
    for (int j_ = 0; j_ < 8; ++j_) {                                           \
        float pj_ = bperm(bpp[j_], p_);                                        \
        f32x2 pj2_ = (f32x2){pj_, pj_};                                        \
        auto lo_ = __builtin_amdgcn_cvt_pk_f32_fp8((int)(C).hv[j_], false);    \
        auto hi_ = __builtin_amdgcn_cvt_pk_f32_fp8((int)(C).hv[j_], true);     \
        f32x2 lov_ = (f32x2){lo_[0], lo_[1]};                                  \
        f32x2 hiv_ = (f32x2){hi_[0], hi_[1]};                                  \
        acc01 += pj2_ * lov_;                                                  \
        acc23 += pj2_ * hiv_;                                                  \
    }                                                                          \
} while (0)

            {
                int i = 0;
                LOADC1(A, 0);
                while (i + 8 < cnt) {
                    LOADC1(B, i + 8);
                    CONSC1(A, i);
                    i += 8;
                    if (i + 8 < cnt) {
                        LOADC1(A, i + 8);
                        CONSC1(B, i);
                        i += 8;
                    } else {
                        CONSC1(B, i);
                        goto done1;
                    }
                }
                CONSC1(A, i);
done1:;
            }
#undef LOADC1
#undef CONSC1

            float ps = s + bperm(ax8, s);
            ps += bperm(ax16, ps);
            ps += bperm(ax32, ps);
            float inv = 1.f / (ps + 1e-16f);
            float inv_a = bperm(bpc, inv);
            float4 o;
            o.x = acc01[0] * inv_a + bv.x;
            o.y = acc01[1] * inv_a + bv.y;
            o.z = acc23[0] * inv_a + bv.z;
            o.w = acc23[1] * inv_a + bv.w;
            o.x = (o.x > 0.f) ? o.x : (__expf(o.x) - 1.f);
            o.y = (o.y > 0.f) ? o.y : (__expf(o.y) - 1.f);
            o.z = (o.z > 0.f) ? o.z : (__expf(o.z) - 1.f);
            o.w = (o.w > 0.f) ? o.w : (__expf(o.w) - 1.f);
            uint2 ov;
            ov.x = packbf(o.x, o.y);
            ov.y = packbf(o.z, o.w);
            *(uint2*)(Xs + node_local * 132 + lane * 2) = ov;
        } else {
            *(uint2*)(Xs + node_local * 132 + lane * 2) = make_uint2(0u, 0u);
        }
    }
    __syncthreads();

    // ---- phase 2: gemm2 (waves 0-3), Xs tile in place ----
    int m = lane & 15;
    int q4 = (lane >> 4) * 4;
    bf16x8 Af[8];
    if (w < 4) {
#pragma unroll
        for (int ks = 0; ks < 8; ++ks) {
            U8 a;
            a.u = *(const uint4*)(Xs + (w * 16 + m) * 132 + ks * 16 + q4);
            Af[ks] = a.v;
        }
    }
    __syncthreads();

    if (w < 4) {
        f32x4 acc[3];
#pragma unroll
        for (int i = 0; i < 3; ++i) acc[i] = (f32x4){0.f, 0.f, 0.f, 0.f};

        const bf16x8* Bf = (const bf16x8*)Wb2;
#pragma unroll
        for (int ks = 0; ks < 8; ++ks) {
#pragma unroll
            for (int nt = 0; nt < 3; ++nt) {
                bf16x8 bvv = Bf[(size_t)(nt * 8 + ks) * 64 + lane];
                acc[nt] = __builtin_amdgcn_mfma_f32_16x16x32_bf16(Af[ks], bvv, acc[nt], 0, 0, 0);
            }
        }

        int cc = lane & 15;
        int r0 = (lane >> 4) * 4;
        uchar* CsB = (uchar*)Xs;
#pragma unroll
        for (int nt = 0; nt < 2; ++nt) {
#pragma unroll
            for (int r = 0; r < 4; ++r)
                CsB[(w * 16 + r0 + r) * 64 + nt * 16 + cc] = f2fp8(acc[nt][r]);
        }
#pragma unroll
        for (int r = 0; r < 4; ++r) {
            int row = (w * 16 + r0 + r) * 64;
            if (cc < 8)       CsB[row + 32 + cc] = f2fp8(acc[2][r]);
            else if (cc == 8) *(float*)(CsB + row + 40) = acc[2][r];  // a2_src
            else if (cc == 9) *(float*)(CsB + row + 44) = acc[2][r];  // a2_dst
            else if (cc == 10) *(uint*)(CsB + row + 48) = 0u;         // pad
            else if (cc == 11) *(uint*)(CsB + row + 52) = 0u;
            else if (cc == 12) *(uint*)(CsB + row + 56) = 0u;
            else if (cc == 13) *(uint*)(CsB + row + 60) = 0u;
        }
    }
    __syncthreads();

    if (t < 256) {
        const uchar* CsB = (const uchar*)Xs;
        int node_local = t >> 2;
        int q = t & 3;
        int gn = n0 + node_local;
        if (gn < n)
            *(uint4*)(h2f8 + (size_t)gn * 64 + q * 16) =
                *(const uint4*)(CsB + node_local * 64 + q * 16);
    }
}

// ---------------- Layer-2 aggregation + bias + log_softmax ----
// Round-6 proven form: sv_pad precompute, 2-deep A/B, no per-j branches.
__global__ __launch_bounds__(256)
void k_agg2(const uchar* __restrict__ h2f8, const float* __restrict__ b2,
            const int* __restrict__ deg, const int* __restrict__ srcs,
            int n, float* __restrict__ out) {
    int wid = blockIdx.x * 4 + (threadIdx.x >> 6);
    if (wid >= n) return;
    wid = __builtin_amdgcn_readfirstlane(wid);
    int lane = threadIdx.x & 63;
    int vj = lane & 7;
    bool live = lane < NCLASS;
    int col = live ? lane : 0;
    const char* h2b = (const char*)h2f8;
    float adn = *(const float*)(h2b + (size_t)wid * 64 + 44);   // embedded a2_dst
    int ax1 = (lane ^ 1) << 2;
    int ax2 = (lane ^ 2) << 2;
    int ax4 = (lane ^ 4) << 2;
    int bpj[8];
#pragma unroll
    for (int j = 0; j < 8; ++j) bpj[j] = j << 2;

    int degw = __builtin_amdgcn_readfirstlane(deg[wid]);
    degw = (degw < 63) ? degw : 63;
    int cnt = degw + 1;
    int sv_full = srcs[((size_t)wid << 6) + lane];
    int sv_pad = (lane < degw) ? sv_full : wid;

    float s = 0.f, acc = 0.f;

    struct Chunk2 { float av; uint hb[8]; };
    Chunk2 A, B;

#define LOADC2(C, base) do {                                                   \
    int idxl_ = (base) + vj;                                                   \
    int svv_ = bperm_i(idxl_ << 2, sv_pad);                                    \
    (C).av = *(const float*)(h2b + ((size_t)(uint)svv_ << 6) + 40u);           \
    _Pragma("unroll")                                                          \
    for (int j_ = 0; j_ < 8; ++j_) {                                           \
        int sn_ = __builtin_amdgcn_readlane(sv_pad, (base) + j_);              \
        (C).hb[j_] = h2f8[(size_t)(uint)sn_ * 64 + col];                       \
    }                                                                          \
} while (0)

#define CONSC2(C, base) do {                                                   \
    int idxl_ = (base) + vj;                                                   \
    float a_ = (C).av + adn;                                                   \
    float e_ = fmaxf(a_, 0.2f * a_);                                           \
    float p_ = (idxl_ < cnt) ? __builtin_exp2f(e_) : 0.f;                      \
    s += p_;                                                                   \
    _Pragma("unroll")                                                          \
    for (int j_ = 0; j_ < 8; ++j_) {                                           \
        float pj_ = bperm(bpj[j_], p_);                                        \
        acc += pj_ * fp8tof((C).hb[j_]);                                       \
    }                                                                          \
} while (0)

    int i = 0;
    LOADC2(A, 0);
    while (i + 8 < cnt) {
        LOADC2(B, i + 8);
        CONSC2(A, i);
        i += 8;
        if (i + 8 < cnt) {
            LOADC2(A, i + 8);
            CONSC2(B, i);
            i += 8;
        } else {
            CONSC2(B, i);
            goto tail2;
        }
    }
    CONSC2(A, i);
tail2:;
#undef LOADC2
#undef CONSC2

    // cross-slot sum tree, once
    float ps = s + bperm(ax1, s);
    ps += bperm(ax2, ps);
    ps += bperm(ax4, ps);

    float val0 = acc / (ps + 1e-16f) + (live ? b2[lane] : 0.f);
    float vmax = live ? val0 : -INFINITY;
#pragma unroll
    for (int msk = 1; msk < 64; msk <<= 1) vmax = fmaxf(vmax, __shfl_xor(vmax, msk, 64));
    float ex = live ? __expf(val0 - vmax) : 0.f;
#pragma unroll
    for (int msk = 1; msk < 64; msk <<= 1) ex += __shfl_xor(ex, msk, 64);
    float res = val0 - vmax - __logf(ex);
    if (live) out[(size_t)wid * NCLASS + lane] = res;
}

// ---------------- launch ----------------
extern "C" void kernel_launch(void* const* d_in, const int* in_sizes, int n_in,
                              void* d_out, int out_size, void* d_ws, size_t ws_size,
                              hipStream_t stream) {
    const float* x    = (const float*)d_in[0];
    const int*   ei   = (const int*)  d_in[1];
    const float* W1   = (const float*)d_in[2];
    const float* attS = (const float*)d_in[3];
    const float* attD = (const float*)d_in[4];
    const float* b1   = (const float*)d_in[5];
    const float* W2   = (const float*)d_in[6];
    const float* a2sw = (const float*)d_in[7];
    const float* a2dw = (const float*)d_in[8];
    const float* b2   = (const float*)d_in[9];

    int n = in_sizes[0] / NFEAT;
    int E = in_sizes[1] / 2;
    const int* srcE = ei;
    const int* dstE = ei + E;
    int mblocks = (n + 63) / 64;

    char* p = (char*)d_ws;
    auto alloc = [&](size_t bytes) {
        char* r = p;
        p += (bytes + 255) & ~(size_t)255;
        return r;
    };
    uchar*  h1f8 = (uchar*)alloc((size_t)n * HC);
    uchar*  h2f8 = (uchar*)alloc((size_t)n * 64);
    ushort* Wb1  = (ushort*)alloc((size_t)17 * 4 * 64 * 8 * 2);
    ushort* Wb2  = (ushort*)alloc((size_t)3 * 8 * 64 * 8 * 2);
    float* a1x = (float*)alloc((size_t)n * 16 * 4);
    int* deg  = (int*)alloc((size_t)n * 4);
    int* rank = (int*)alloc((size_t)E * 4);
    int* srcs = (int*)alloc((size_t)n * 64 * 4);   // padded CSR [n][64]

    int histb = (E + 256 * HU - 1) / (256 * HU);
    int P = (E + 3) / 4;
    int scb = (P + 256 * SU - 1) / (256 * SU);
    hipMemsetAsync(deg, 0, (size_t)n * 4, stream);
    k_hist_prep<<<PREPB + histb, 256, 0, stream>>>(dstE, E, deg, rank,
                                                   W1, attS, attD, W2, a2sw, a2dw,
                                                   Wb1, Wb2);
    k_scatter_gemm1<<<scb + mblocks, 256, 0, stream>>>(
        srcE, dstE, rank, E, srcs, scb, x, Wb1, n, h1f8, a1x);
    k_agg1_gemm2<<<mblocks, 1024, 0, stream>>>((const uint*)h1f8, a1x, b1,
                                               deg, srcs, Wb2, n, h2f8);
    k_agg2<<<(n + 3) / 4, 256, 0, stream>>>(h2f8, b2, deg, srcs, n, (float*)d_out);
}

// Round 10
// 222.316 us; speedup vs baseline: 1.0762x; 1.0762x over previous
//
#include <hip/hip_runtime.h>
#include <math.h>

#define NFEAT  128
#define HC     256     // HEADS*NHID
#define HEADS  8
#define NHID   32
#define NCLASS 40

#define INV_LN2 1.44269504088896340736f

typedef unsigned int  uint;
typedef unsigned short ushort;
typedef unsigned char uchar;

typedef __attribute__((ext_vector_type(8))) short bf16x8;
typedef __attribute__((ext_vector_type(4))) float f32x4;
typedef __attribute__((ext_vector_type(2))) float f32x2;

union U8 { uint4 u; bf16x8 v; };

// bf16 helpers (RNE pack, cheap unpack)
__device__ __forceinline__ uint f2bf1(float f) {
    uint b = __float_as_uint(f);
    b += 0x7FFFu + ((b >> 16) & 1u);
    return b >> 16;
}
__device__ __forceinline__ uint packbf(float lo, float hi) {
    return f2bf1(lo) | (f2bf1(hi) << 16);
}

// fp8 e4m3 (OCP) via HW converts
__device__ __forceinline__ uchar f2fp8(float v) {
    return (uchar)(__builtin_amdgcn_cvt_pk_fp8_f32(v, v, 0, false) & 0xFF);
}
__device__ __forceinline__ float fp8tof(uint byte) {
    auto v2 = __builtin_amdgcn_cvt_pk_f32_fp8((int)byte, false);
    return v2[0];
}

// cross-lane pull with precomputed byte address (addr = src_lane*4)
__device__ __forceinline__ float bperm(int addr, float v) {
    return __int_as_float(__builtin_amdgcn_ds_bpermute(addr, __float_as_int(v)));
}
__device__ __forceinline__ int bperm_i(int addr, int v) {
    return __builtin_amdgcn_ds_bpermute(addr, v);
}

// ---------------- hist (rank only, coalesced store) + weight prep ----------------
// Proven form (r5/r7): atomic return feeds a COALESCED rank store; the random
// scatter is a separate streaming phase fused with gemm1.

#define HU 8
#define PREPB 23
__global__ __launch_bounds__(256)
void k_hist_prep(const int* __restrict__ dst, int E, int* deg,
                 int* __restrict__ rank,
                 const float* __restrict__ W1,
                 const float* __restrict__ attS, const float* __restrict__ attD,
                 const float* __restrict__ W2,
                 const float* __restrict__ a2sw, const float* __restrict__ a2dw,
                 ushort* __restrict__ Wb1, ushort* __restrict__ Wb2) {
    int blk = blockIdx.x;
    int t = threadIdx.x;
    if (blk >= PREPB) {
        int tid = (blk - PREPB) * 256 + t;
        int stride = (gridDim.x - PREPB) * 256;
#pragma unroll
        for (int j = 0; j < HU; ++j) {
            int i = tid + j * stride;
            if (i < E) rank[i] = atomicAdd(&deg[dst[i]], 1);
        }
        return;
    }
    // ---- prep ----
    float f[8];
    if (blk < 17) {
        int g = blk * 256 + t;
        int lane = g & 63;
        int step = (g >> 6) & 3;
        int tile = g >> 8;
        int k0 = step * 32 + (lane >> 4) * 8;
        if (tile < 16) {
            int ncol = tile * 16 + (lane & 15);
#pragma unroll
            for (int j = 0; j < 8; ++j) f[j] = W1[(size_t)(k0 + j) * HC + ncol];
        } else {
            int cc = lane & 15;
            int h = cc & 7;
            const float* av = (cc < 8) ? attS : attD;
#pragma unroll
            for (int j = 0; j < 8; ++j) {
                const float* wr = W1 + (size_t)(k0 + j) * HC + h * 32;
                float s = 0.f;
#pragma unroll
                for (int c = 0; c < 32; ++c) s += wr[c] * av[h * 32 + c];
                f[j] = s * INV_LN2;   // exp2-domain attention logits
            }
        }
        uint4 o;
        o.x = packbf(f[0], f[1]);
        o.y = packbf(f[2], f[3]);
        o.z = packbf(f[4], f[5]);
        o.w = packbf(f[6], f[7]);
        *(uint4*)(Wb1 + (size_t)g * 8) = o;
    } else {
        int g = (blk - 17) * 256 + t;      // 0..1535
        if (g >= 3 * 8 * 64) return;
        int lane = g & 63;
        int ks = (g >> 6) & 7;
        int nt = g >> 9;
        int cc = lane & 15;
        int ncol = nt * 16 + cc;
        int k0 = ks * 32 + (lane >> 4) * 8;
        if (ncol < NCLASS) {
#pragma unroll
            for (int j = 0; j < 8; ++j) f[j] = W2[(size_t)(k0 + j) * NCLASS + ncol];
        } else if (ncol <= 41) {
            const float* av = (ncol == 40) ? a2sw : a2dw;
#pragma unroll
            for (int j = 0; j < 8; ++j) {
                const float* wr = W2 + (size_t)(k0 + j) * NCLASS;
                float s = 0.f;
#pragma unroll
                for (int c = 0; c < NCLASS; ++c) s += wr[c] * av[c];
                f[j] = s * INV_LN2;   // exp2-domain attention logits
            }
        } else {
#pragma unroll
            for (int j = 0; j < 8; ++j) f[j] = 0.f;
        }
        uint4 o;
        o.x = packbf(f[0], f[1]);
        o.y = packbf(f[2], f[3]);
        o.z = packbf(f[4], f[5]);
        o.w = packbf(f[6], f[7]);
        *(uint4*)(Wb2 + (size_t)g * 8) = o;
    }
}

// ---------------- fused scatter + GEMM1 ----------------
// srcs rows are USHORT[64] (node ids < 65536): 128B rows, rank<=16 writes land
// in ONE 64B line per row (was 2 with int rows) -> scatter write-allocate
// traffic ~halves; agg slot-row reads halve; srcs footprint 6.4 MB.
#define SU 4
__global__ __launch_bounds__(256)
void k_scatter_gemm1(const int* __restrict__ srcE, const int* __restrict__ dstE,
                     const int* __restrict__ rank, int E,
                     ushort* __restrict__ srcs, int scb,
                     const float* __restrict__ x, const ushort* __restrict__ Wb,
                     int n, uchar* __restrict__ h1f8, float* __restrict__ a1x) {
    __shared__ uint Xs[64 * 68];        // 17.4 KB; aliased as Cs[64][272]B later
    int t = threadIdx.x;
    if (blockIdx.x < scb) {
        // ---- scatter: 4-edge packets, vectorized streaming loads ----
        int tid = blockIdx.x * 256 + t;
        int stride = scb * 256;
        int P = (E + 3) >> 2;
#pragma unroll
        for (int g = 0; g < SU; ++g) {
            int pk = tid + g * stride;
            if (pk >= P) continue;
            int i0 = pk * 4;
            if (i0 + 4 <= E) {
                int4 d4 = *(const int4*)(dstE + i0);
                int4 r4 = *(const int4*)(rank + i0);
                int4 s4 = *(const int4*)(srcE + i0);
                if (r4.x < 64) srcs[((size_t)d4.x << 6) + r4.x] = (ushort)s4.x;
                if (r4.y < 64) srcs[((size_t)d4.y << 6) + r4.y] = (ushort)s4.y;
                if (r4.z < 64) srcs[((size_t)d4.z << 6) + r4.z] = (ushort)s4.z;
                if (r4.w < 64) srcs[((size_t)d4.w << 6) + r4.w] = (ushort)s4.w;
            } else {
                for (int i = i0; i < E; ++i) {
                    int r = rank[i];
                    if (r < 64) srcs[((size_t)dstE[i] << 6) + r] = (ushort)srcE[i];
                }
            }
        }
        return;
    }
    // ---- gemm1 ----
    int lane = t & 63;
    int w = t >> 6;
    int n0 = (blockIdx.x - scb) * 64;

#pragma unroll
    for (int j = 0; j < 8; ++j) {
        int f4 = t + j * 256;
        int node = f4 >> 5;
        int k4 = (f4 & 31) * 4;
        int gn = n0 + node;
        float4 v = make_float4(0.f, 0.f, 0.f, 0.f);
        if (gn < n) v = *(const float4*)(x + (size_t)gn * NFEAT + k4);
        uint2 pk;
        pk.x = packbf(v.x, v.y);
        pk.y = packbf(v.z, v.w);
        *(uint2*)(Xs + node * 68 + (k4 >> 1)) = pk;
    }
    __syncthreads();

    int m = lane & 15;
    int q4 = (lane >> 4) * 4;
    bf16x8 Af[4];
#pragma unroll
    for (int ks = 0; ks < 4; ++ks) {
        U8 a;
        a.u = *(const uint4*)(Xs + (w * 16 + m) * 68 + ks * 16 + q4);
        Af[ks] = a.v;
    }
    __syncthreads();

    f32x4 acc[17];
#pragma unroll
    for (int i = 0; i < 17; ++i) acc[i] = (f32x4){0.f, 0.f, 0.f, 0.f};

    const bf16x8* Bf = (const bf16x8*)Wb;
#pragma unroll
    for (int ks = 0; ks < 4; ++ks) {
#pragma unroll
        for (int nt = 0; nt < 17; ++nt) {
            bf16x8 bv = Bf[(size_t)(nt * 4 + ks) * 64 + lane];
            acc[nt] = __builtin_amdgcn_mfma_f32_16x16x32_bf16(Af[ks], bv, acc[nt], 0, 0, 0);
        }
    }

    int cc = lane & 15;
    int r0 = (lane >> 4) * 4;

    // attention tile (nt=16): col cc -> a1x[gn*16+cc] (0..7 src heads, 8..15 dst)
#pragma unroll
    for (int r = 0; r < 4; ++r) {
        int gn = n0 + w * 16 + r0 + r;
        if (gn < n) a1x[(size_t)gn * 16 + cc] = acc[16][r];
    }

    uchar* CsB = (uchar*)Xs;
#pragma unroll
    for (int nt = 0; nt < 16; ++nt) {
#pragma unroll
        for (int r = 0; r < 4; ++r)
            CsB[(w * 16 + r0 + r) * 272 + nt * 16 + cc] = f2fp8(acc[nt][r]);
    }
    __syncthreads();

    int node_local = t >> 2;
    int q = t & 3;
    int gn = n0 + node_local;
    if (gn < n) {
        const uchar* crow = CsB + node_local * 272 + q * 64;
        uchar* hp = h1f8 + (size_t)gn * HC + q * 64;
#pragma unroll
        for (int i = 0; i < 4; ++i)
            *(uint4*)(hp + i * 16) = *(const uint4*)(crow + i * 16);
    }
}

// ---------------- Layer-1 aggregation: one wave per dst node ----------------
// ushort padded rows loaded ONCE as packed uint pairs (128B, coalesced);
// pad/self slots pre-mapped to wid in the PACK (one-time). Per chunk: slot
// value via 1 bperm + half-select (vector) and 4 readlanes + scalar bfe
// (scalar h-row bases). 2-deep A/B pipeline, NO per-j branches (r7 lesson).
// Global-shift softmax (logits bounded), f32x2 pk-fma accumulate.
__global__ __launch_bounds__(256)
void k_agg1(const uint* __restrict__ h1u, const float* __restrict__ a1x,
            const float* __restrict__ b1, const int* __restrict__ deg,
            const ushort* __restrict__ srcs,
            int n, ushort* __restrict__ hgb) {
    int wid = blockIdx.x * 4 + (threadIdx.x >> 6);
    if (wid >= n) return;
    wid = __builtin_amdgcn_readfirstlane(wid);
    int lane = threadIdx.x & 63;
    int vj = lane >> 3;          // attention layout: edge slot
    int hh = lane & 7;           // attention layout: head
    int hacc = lane >> 3;        // accumulation layout: head of this row-dword
    float adn = a1x[(size_t)wid * 16 + 8 + hh];
    const char* a1xb = (const char*)a1x;
    int ax8  = (lane ^ 8)  << 2;
    int ax16 = (lane ^ 16) << 2;
    int ax32 = (lane ^ 32) << 2;
    int bpc  = hacc << 2;
    int bpp[8];
#pragma unroll
    for (int j = 0; j < 8; ++j) bpp[j] = ((j << 3) + hacc) << 2;

    int degw = __builtin_amdgcn_readfirstlane(deg[wid]);
    degw = (degw < 63) ? degw : 63;      // defensive clamp
    int cnt = degw + 1;                  // + virtual self-loop
    // packed slot pair (slots 2*(lane&31), 2*(lane&31)+1), padded to wid
    uint su = ((const uint*)(srcs + ((size_t)wid << 6)))[lane & 31];
    int sl0 = (lane & 31) * 2;
    int p0 = (sl0 < degw) ? (int)(su & 0xFFFFu) : wid;
    int p1 = (sl0 + 1 < degw) ? (int)(su >> 16) : wid;
    int pack = p0 | (p1 << 16);

    float s = 0.f;
    f32x2 acc01 = (f32x2){0.f, 0.f};
    f32x2 acc23 = (f32x2){0.f, 0.f};

    struct Chunk { float av; uint hv[8]; };
    Chunk A, B;

#define LOADC1(C, base) do {                                                   \
    int idxl_ = (base) + vj;                                                   \
    uint pu_ = (uint)bperm_i((idxl_ >> 1) << 2, pack);                         \
    int sv_ = (idxl_ & 1) ? (int)(pu_ >> 16) : (int)(pu_ & 0xFFFFu);           \
    (C).av = *(const float*)(a1xb + ((size_t)(uint)sv_ << 6) + ((uint)hh << 2)); \
    _Pragma("unroll")                                                          \
    for (int jp_ = 0; jp_ < 4; ++jp_) {                                        \
        int sp_ = __builtin_amdgcn_readlane(pack, ((base) >> 1) + jp_);        \
        int snA_ = sp_ & 0xFFFF;                                               \
        int snB_ = (int)(((uint)sp_) >> 16);                                   \
        (C).hv[2 * jp_]     = h1u[(size_t)snA_ * 64 + lane];                   \
        (C).hv[2 * jp_ + 1] = h1u[(size_t)snB_ * 64 + lane];                   \
    }                                                                          \
} while (0)

#define CONSC1(C, base) do {                                                   \
    int idxl_ = (base) + vj;                                                   \
    float a_ = (C).av + adn;                                                   \
    float e_ = fmaxf(a_, 0.2f * a_);                                           \
    float p_ = (idxl_ < cnt) ? __builtin_exp2f(e_) : 0.f;                      \
    s += p_;                                                                   \
    _Pragma("unroll")                                                          \
    for (int j_ = 0; j_ < 8; ++j_) {                                           \
        float pj_ = bperm(bpp[j_], p_);                                        \
        f32x2 pj2_ = (f32x2){pj_, pj_};                                        \
        auto lo_ = __builtin_amdgcn_cvt_pk_f32_fp8((int)(C).hv[j_], false);    \
        auto hi_ = __builtin_amdgcn_cvt_pk_f32_fp8((int)(C).hv[j_], true);     \
        f32x2 lov_ = (f32x2){lo_[0], lo_[1]};                                  \
        f32x2 hiv_ = (f32x2){hi_[0], hi_[1]};                                  \
        acc01 += pj2_ * lov_;                                                  \
        acc23 += pj2_ * hiv_;                                                  \
    }                                                                          \
} while (0)

    int i = 0;
    LOADC1(A, 0);
    while (i + 8 < cnt) {
        LOADC1(B, i + 8);
        CONSC1(A, i);
        i += 8;
        if (i + 8 < cnt) {
            LOADC1(A, i + 8);
            CONSC1(B, i);
            i += 8;
        } else {
            CONSC1(B, i);
            goto tail1;
        }
    }
    CONSC1(A, i);
tail1:;
#undef LOADC1
#undef CONSC1

    // cross-j sum tree, once
    float ps = s + bperm(ax8, s);
    ps += bperm(ax16, ps);
    ps += bperm(ax32, ps);
    float inv = 1.f / (ps + 1e-16f);
    float inv_a = bperm(bpc, inv);
    float4 bv = *(const float4*)(b1 + lane * 4);
    float4 o;
    o.x = acc01[0] * inv_a + bv.x;
    o.y = acc01[1] * inv_a + bv.y;
    o.z = acc23[0] * inv_a + bv.z;
    o.w = acc23[1] * inv_a + bv.w;
    o.x = (o.x > 0.f) ? o.x : (__expf(o.x) - 1.f);
    o.y = (o.y > 0.f) ? o.y : (__expf(o.y) - 1.f);
    o.z = (o.z > 0.f) ? o.z : (__expf(o.z) - 1.f);
    o.w = (o.w > 0.f) ? o.w : (__expf(o.w) - 1.f);
    uint2 ov;
    ov.x = packbf(o.x, o.y);
    ov.y = packbf(o.z, o.w);
    *(uint2*)(hgb + (size_t)wid * HC + lane * 4) = ov;
}

// ---------------- GEMM2 (MFMA bf16): h2 = hg @ W2, fp8 h2 out (64B rows) ----
__global__ __launch_bounds__(256)
void k_gemm2(const ushort* __restrict__ hgb, const ushort* __restrict__ Wb2,
             int n, uchar* __restrict__ h2f8) {
    __shared__ uint Xs[64 * 132];       // 33.8 KB; aliased as Cs[64][64]B later
    int t = threadIdx.x;
    int lane = t & 63;
    int w = t >> 6;
    int n0 = blockIdx.x * 64;

#pragma unroll
    for (int j = 0; j < 8; ++j) {
        int g = t + j * 256;
        int node = g >> 5;
        int u4 = g & 31;
        int gn = n0 + node;
        uint4 v = make_uint4(0u, 0u, 0u, 0u);
        if (gn < n) v = *(const uint4*)(hgb + (size_t)gn * HC + u4 * 8);
        *(uint4*)(Xs + node * 132 + u4 * 4) = v;
    }
    __syncthreads();

    int m = lane & 15;
    int q4 = (lane >> 4) * 4;
    bf16x8 Af[8];
#pragma unroll
    for (int ks = 0; ks < 8; ++ks) {
        U8 a;
        a.u = *(const uint4*)(Xs + (w * 16 + m) * 132 + ks * 16 + q4);
        Af[ks] = a.v;
    }
    __syncthreads();

    f32x4 acc[3];
#pragma unroll
    for (int i = 0; i < 3; ++i) acc[i] = (f32x4){0.f, 0.f, 0.f, 0.f};

    const bf16x8* Bf = (const bf16x8*)Wb2;
#pragma unroll
    for (int ks = 0; ks < 8; ++ks) {
#pragma unroll
        for (int nt = 0; nt < 3; ++nt) {
            bf16x8 bv = Bf[(size_t)(nt * 8 + ks) * 64 + lane];
            acc[nt] = __builtin_amdgcn_mfma_f32_16x16x32_bf16(Af[ks], bv, acc[nt], 0, 0, 0);
        }
    }

    int cc = lane & 15;
    int r0 = (lane >> 4) * 4;

    uchar* CsB = (uchar*)Xs;
#pragma unroll
    for (int nt = 0; nt < 2; ++nt) {
#pragma unroll
        for (int r = 0; r < 4; ++r)
            CsB[(w * 16 + r0 + r) * 64 + nt * 16 + cc] = f2fp8(acc[nt][r]);
    }
#pragma unroll
    for (int r = 0; r < 4; ++r) {
        int row = (w * 16 + r0 + r) * 64;
        if (cc < 8)       CsB[row + 32 + cc] = f2fp8(acc[2][r]);
        else if (cc == 8) *(float*)(CsB + row + 40) = acc[2][r];  // a2_src (exp2-dom)
        else if (cc == 9) *(float*)(CsB + row + 44) = acc[2][r];  // a2_dst (exp2-dom)
        else if (cc == 10) *(uint*)(CsB + row + 48) = 0u;         // pad (defined)
        else if (cc == 11) *(uint*)(CsB + row + 52) = 0u;
        else if (cc == 12) *(uint*)(CsB + row + 56) = 0u;
        else if (cc == 13) *(uint*)(CsB + row + 60) = 0u;
    }
    __syncthreads();

    int node_local = t >> 2;
    int q = t & 3;
    int gn = n0 + node_local;
    if (gn < n)
        *(uint4*)(h2f8 + (size_t)gn * 64 + q * 16) =
            *(const uint4*)(CsB + node_local * 64 + q * 16);
}

// ---------------- Layer-2 aggregation + bias + log_softmax ----
// Same packed-row structure as k_agg1. Lane slot j = lane&7 (p replicated x8
// -> s wave-uniform after stride-{1,2,4} tree). 2-deep A/B, no per-j branches.
__global__ __launch_bounds__(256)
void k_agg2(const uchar* __restrict__ h2f8, const float* __restrict__ b2,
            const int* __restrict__ deg, const ushort* __restrict__ srcs,
            int n, float* __restrict__ out) {
    int wid = blockIdx.x * 4 + (threadIdx.x >> 6);
    if (wid >= n) return;
    wid = __builtin_amdgcn_readfirstlane(wid);
    int lane = threadIdx.x & 63;
    int vj = lane & 7;
    bool live = lane < NCLASS;
    int col = live ? lane : 0;
    const char* h2b = (const char*)h2f8;
    float adn = *(const float*)(h2b + (size_t)wid * 64 + 44);   // embedded a2_dst
    int ax1 = (lane ^ 1) << 2;
    int ax2 = (lane ^ 2) << 2;
    int ax4 = (lane ^ 4) << 2;
    int bpj[8];
#pragma unroll
    for (int j = 0; j < 8; ++j) bpj[j] = j << 2;

    int degw = __builtin_amdgcn_readfirstlane(deg[wid]);
    degw = (degw < 63) ? degw : 63;
    int cnt = degw + 1;
    uint su = ((const uint*)(srcs + ((size_t)wid << 6)))[lane & 31];
    int sl0 = (lane & 31) * 2;
    int p0 = (sl0 < degw) ? (int)(su & 0xFFFFu) : wid;
    int p1 = (sl0 + 1 < degw) ? (int)(su >> 16) : wid;
    int pack = p0 | (p1 << 16);

    float s = 0.f, acc = 0.f;

    struct Chunk2 { float av; uint hb[8]; };
    Chunk2 A, B;

#define LOADC2(C, base) do {                                                   \
    int idxl_ = (base) + vj;                                                   \
    uint pu_ = (uint)bperm_i((idxl_ >> 1) << 2, pack);                         \
    int sv_ = (idxl_ & 1) ? (int)(pu_ >> 16) : (int)(pu_ & 0xFFFFu);           \
    (C).av = *(const float*)(h2b + ((size_t)(uint)sv_ << 6) + 40u);            \
    _Pragma("unroll")                                                          \
    for (int jp_ = 0; jp_ < 4; ++jp_) {                                        \
        int sp_ = __builtin_amdgcn_readlane(pack, ((base) >> 1) + jp_);        \
        int snA_ = sp_ & 0xFFFF;                                               \
        int snB_ = (int)(((uint)sp_) >> 16);                                   \
        (C).hb[2 * jp_]     = h2f8[(size_t)snA_ * 64 + col];                   \
        (C).hb[2 * jp_ + 1] = h2f8[(size_t)snB_ * 64 + col];                   \
    }                                                                          \
} while (0)

#define CONSC2(C, base) do {                                                   \
    int idxl_ = (base) + vj;                                                   \
    float a_ = (C).av + adn;                                                   \
    float e_ = fmaxf(a_, 0.2f * a_);                                           \
    float p_ = (idxl_ < cnt) ? __builtin_exp2f(e_) : 0.f;                      \
    s += p_;                                                                   \
    _Pragma("unroll")                                                          \
    for (int j_ = 0; j_ < 8; ++j_) {                                           \
        float pj_ = bperm(bpj[j_], p_);                                        \
        acc += pj_ * fp8tof((C).hb[j_]);                                       \
    }                                                                          \
} while (0)

    int i = 0;
    LOADC2(A, 0);
    while (i + 8 < cnt) {
        LOADC2(B, i + 8);
        CONSC2(A, i);
        i += 8;
        if (i + 8 < cnt) {
            LOADC2(A, i + 8);
            CONSC2(B, i);
            i += 8;
        } else {
            CONSC2(B, i);
            goto tail2;
        }
    }
    CONSC2(A, i);
tail2:;
#undef LOADC2
#undef CONSC2

    // cross-slot sum tree, once
    float ps = s + bperm(ax1, s);
    ps += bperm(ax2, ps);
    ps += bperm(ax4, ps);

    float val0 = acc / (ps + 1e-16f) + (live ? b2[lane] : 0.f);
    float vmax = live ? val0 : -INFINITY;
#pragma unroll
    for (int msk = 1; msk < 64; msk <<= 1) vmax = fmaxf(vmax, __shfl_xor(vmax, msk, 64));
    float ex = live ? __expf(val0 - vmax) : 0.f;
#pragma unroll
    for (int msk = 1; msk < 64; msk <<= 1) ex += __shfl_xor(ex, msk, 64);
    float res = val0 - vmax - __logf(ex);
    if (live) out[(size_t)wid * NCLASS + lane] = res;
}

// ---------------- launch ----------------
extern "C" void kernel_launch(void* const* d_in, const int* in_sizes, int n_in,
                              void* d_out, int out_size, void* d_ws, size_t ws_size,
                              hipStream_t stream) {
    const float* x    = (const float*)d_in[0];
    const int*   ei   = (const int*)  d_in[1];
    const float* W1   = (const float*)d_in[2];
    const float* attS = (const float*)d_in[3];
    const float* attD = (const float*)d_in[4];
    const float* b1   = (const float*)d_in[5];
    const float* W2   = (const float*)d_in[6];
    const float* a2sw = (const float*)d_in[7];
    const float* a2dw = (const float*)d_in[8];
    const float* b2   = (const float*)d_in[9];

    int n = in_sizes[0] / NFEAT;
    int E = in_sizes[1] / 2;
    const int* srcE = ei;
    const int* dstE = ei + E;
    int mblocks = (n + 63) / 64;

    char* p = (char*)d_ws;
    auto alloc = [&](size_t bytes) {
        char* r = p;
        p += (bytes + 255) & ~(size_t)255;
        return r;
    };
    uchar*  h1f8 = (uchar*)alloc((size_t)n * HC);
    ushort* hgb  = (ushort*)alloc((size_t)n * HC * 2);
    uchar*  h2f8 = (uchar*)alloc((size_t)n * 64);
    ushort* Wb1  = (ushort*)alloc((size_t)17 * 4 * 64 * 8 * 2);
    ushort* Wb2  = (ushort*)alloc((size_t)3 * 8 * 64 * 8 * 2);
    float* a1x = (float*)alloc((size_t)n * 16 * 4);
    int* deg  = (int*)alloc((size_t)n * 4);
    int* rank = (int*)alloc((size_t)E * 4);
    ushort* srcs = (ushort*)alloc((size_t)n * 64 * 2);   // padded CSR [n][64] u16

    int histb = (E + 256 * HU - 1) / (256 * HU);
    int P = (E + 3) / 4;
    int scb = (P + 256 * SU - 1) / (256 * SU);
    hipMemsetAsync(deg, 0, (size_t)n * 4, stream);
    k_hist_prep<<<PREPB + histb, 256, 0, stream>>>(dstE, E, deg, rank,
                                                   W1, attS, attD, W2, a2sw, a2dw,
                                                   Wb1, Wb2);
    k_scatter_gemm1<<<scb + mblocks, 256, 0, stream>>>(
        srcE, dstE, rank, E, srcs, scb, x, Wb1, n, h1f8, a1x);
    k_agg1<<<(n + 3) / 4, 256, 0, stream>>>((const uint*)h1f8, a1x, b1,
                                            deg, srcs, n, hgb);
    k_gemm2<<<mblocks, 256, 0, stream>>>(hgb, Wb2, n, h2f8);
    k_agg2<<<(n + 3) / 4, 256, 0, stream>>>(h2f8, b2, deg, srcs, n, (float*)d_out);
}